// Round 9
// baseline (285.155 us; speedup 1.0000x reference)
//
#include <hip/hip_runtime.h>
#include <math.h>

// Problem shape (fixed by reference setup_inputs):
//   features:  (B=8, N=65536, C=64) fp32
//   coarse_map:(B=8, NP=16384, NS=32) int32 in [0, N)
//   out:       (B, NP, C) fp32 = max over NS gathered rows
constexpr int B  = 8;
constexpr int N  = 65536;
constexpr int C  = 64;      // floats per feature row (256 B)
constexpr int NP = 16384;
constexpr int NS = 32;
constexpr int C4 = C / 4;   // 16 float4 per row

// R9: five schedule variants (R0/R1/R4/R5/R8) all pinned at 3.7 TB/s ->
// that's the L2-miss service ceiling for random 256 B gathers, not an MLP
// artifact. FETCH_SIZE is TCC (L2-miss) traffic; the fix is making the 8x
// row reuse land in the per-XCD 4 MB L2s:
//   * batch = blockIdx.x % 8  -> each XCD (round-robin dispatch, m09/m157)
//     touches ONLY its own batch's 16.7 MB feature table (R7 failure: every
//     XCD cached every batch's band -> 8x duplication -> thrash).
//   * per-point bitonic sort of the 32 indices (R6/R7 machinery, absmax 0.0
//     proven; max is order-invariant, any compare-exchange net is a
//     permutation) -> all blocks of an XCD sweep the table in the same
//     order; instantaneous band ~1.5-3 MB < 4 MB L2.
//   * consumption loop = R0's dense 32-sample loop (3.7 TB/s @ 7% VALU).

constexpr int PPG = 4;                          // points per 16-lane group
constexpr int GPB = 16;                         // groups per block (256 thr)
constexpr int GRID = B * NP / (PPG * GPB);      // 2048 blocks, exact cover

__device__ __forceinline__ int fetch_idx(int2 v, int s, int gbase)
{
    // Owner lane gbase + (s>>1) holds sample s in slot (s&1).
    const int sel = (s & 1) ? v.y : v.x;
    return __shfl(sel, gbase + (s >> 1), 64);
}

// Bitonic sort of 32 ints distributed over 16 lanes (lane j holds elements
// 2j, 2j+1). Element e's direction bit uses (2j)&k, valid for k >= 2.
__device__ __forceinline__ int2 sort32(int2 v, int j)
{
    int a = v.x, c = v.y;
#pragma unroll
    for (int k = 2; k <= 32; k <<= 1) {
#pragma unroll
        for (int jm = 16; jm > 0; jm >>= 1) {
            if (jm > (k >> 1)) continue;       // stages of this pass
            const bool up = (((2 * j) & k) == 0);
            if (jm == 1) {
                const int lo = min(a, c), hi = max(a, c);
                a = up ? lo : hi;
                c = up ? hi : lo;
            } else {
                const int lm = jm >> 1;        // lane xor distance (<16)
                const int pa = __shfl_xor(a, lm, 64);
                const int pc = __shfl_xor(c, lm, 64);
                const bool keepmin = (up == ((j & lm) == 0));
                a = keepmin ? min(a, pa) : max(a, pa);
                c = keepmin ? min(c, pc) : max(c, pc);
            }
        }
    }
    return make_int2(a, c);
}

// 16 lanes cooperate on one output point; lane j owns channels [4j, 4j+4).
// Each gathered row read = 16 lanes x float4 = one contiguous 256 B segment.
__global__ __launch_bounds__(256, 4) void gather_max_kernel(
    const float4* __restrict__ feat,   // B*N*C4 float4
    const int*    __restrict__ cmap,   // B*NP*NS int32
    float4*       __restrict__ out)    // B*NP*C4 float4
{
    const int bid  = blockIdx.x;
    const int b    = bid & 7;              // batch == XCD (round-robin dispatch)
    const int wib  = bid >> 3;             // within-batch block, 0..255
    const int gloc = threadIdx.x >> 4;     // group within block, 0..15
    const int j    = threadIdx.x & 15;     // float4 slot within the row
    const int lane  = threadIdx.x & 63;
    const int gbase = lane & ~15;          // base lane of this 16-lane group

    const int point0 = b * NP + (wib * GPB + gloc) * PPG;  // 4 pts, one batch
    const float4* fbase = feat + (size_t)b * N * C4;

    // Load this group's 4 index lists (lane j holds idx[2j], idx[2j+1],
    // 128 B coalesced per point) and sort each in-register.
    int2 my[PPG];
#pragma unroll
    for (int p = 0; p < PPG; ++p)
        my[p] = ((const int2*)(cmap + (size_t)(point0 + p) * NS))[j];
#pragma unroll
    for (int p = 0; p < PPG; ++p)
        my[p] = sort32(my[p], j);

    // Consumption: R0's dense loop, in ascending index order.
#pragma unroll
    for (int p = 0; p < PPG; ++p) {
        float4 m = make_float4(-INFINITY, -INFINITY, -INFINITY, -INFINITY);
#pragma unroll
        for (int s = 0; s < NS; ++s) {
            const int idx = fetch_idx(my[p], s, gbase);
            const float4 f = fbase[(size_t)idx * C4 + j];
            m.x = fmaxf(m.x, f.x);
            m.y = fmaxf(m.y, f.y);
            m.z = fmaxf(m.z, f.z);
            m.w = fmaxf(m.w, f.w);
        }
        // Coalesced float4 store: 256 B contiguous per point.
        out[(size_t)(point0 + p) * C4 + j] = m;
    }
}

extern "C" void kernel_launch(void* const* d_in, const int* in_sizes, int n_in,
                              void* d_out, int out_size, void* d_ws, size_t ws_size,
                              hipStream_t stream) {
    const float4* feat = (const float4*)d_in[0];
    const int*    cmap = (const int*)d_in[1];
    float4*       out  = (float4*)d_out;

    const int block = 256;
    gather_max_kernel<<<GRID, block, 0, stream>>>(feat, cmap, out);
}

// Round 10
// 275.510 us; speedup vs baseline: 1.0350x; 1.0350x over previous
//
#include <hip/hip_runtime.h>
#include <math.h>

// Problem shape (fixed by reference setup_inputs):
//   features:  (B=8, N=65536, C=64) fp32
//   coarse_map:(B=8, NP=16384, NS=32) int32 in [0, N)
//   out:       (B, NP, C) fp32 = max over NS gathered rows
constexpr int B  = 8;
constexpr int N  = 65536;
constexpr int C  = 64;      // floats per feature row (256 B)
constexpr int NP = 16384;
constexpr int NS = 32;
constexpr int C4 = C / 4;   // 16 float4 per row

typedef int   v2i __attribute__((ext_vector_type(2)));
typedef float v4f __attribute__((ext_vector_type(4)));

// R10: MLP is closed (R0/R1/R4/R5/R8: five schedule shapes, all 3.7 TB/s
// -> per-CU miss-queue HW limit, ~40 lines in flight at ~375 ns), big
// locality is closed (R6/R7/R9: sort/pacing overhead > traffic saving).
// Last lever: L2 pollution. cmap reads (16.8 MB) + output writes (33.5 MB)
// are single-touch streams cycling through the 32 MB aggregate L2 that
// holds the hot feature rows (60% hit rate on 1.07 GB demand). Mark both
// non-temporal (nt-flagged global ops) so they don't evict feature lines.
// Kernel is otherwise byte-for-byte R0 (the best performer, 128 us).

// 16 lanes cooperate on one output point; lane j owns channels [4j, 4j+4).
// Each gathered row read = 16 lanes x float4 = one contiguous 256 B segment.
__global__ __launch_bounds__(256) void gather_max_kernel(
    const float4* __restrict__ feat,   // B*N*C4 float4
    const int*    __restrict__ cmap,   // B*NP*NS int32
    float4*       __restrict__ out)    // B*NP*C4 float4
{
    const int tid   = blockIdx.x * blockDim.x + threadIdx.x;
    const int point = tid >> 4;            // global point id in [0, B*NP)
    const int j     = tid & 15;            // lane-within-group = float4 index
    if (point >= B * NP) return;

    const int    b        = point >> 14;   // point / NP (NP = 16384 = 2^14)
    const size_t featBase = (size_t)b * N * C4;

    // Cooperative index load, NON-TEMPORAL (single-touch stream, keep out of L2):
    // lane j holds idx[2j], idx[2j+1] (coalesced 128 B/group).
    const v2i raw = __builtin_nontemporal_load(
        (const v2i*)(cmap + (size_t)point * NS) + j);
    const int2 myIdx = make_int2(raw.x, raw.y);

    const int lane  = threadIdx.x & 63;
    const int gbase = lane & ~15;          // base lane of this 16-lane group

    float4 m = make_float4(-INFINITY, -INFINITY, -INFINITY, -INFINITY);
#pragma unroll
    for (int s = 0; s < NS; ++s) {
        // Owner lane for sample s is gbase + (s>>1); it holds the value in .x/.y.
        const int v   = (s & 1) ? myIdx.y : myIdx.x;
        const int idx = __shfl(v, gbase + (s >> 1), 64);
        const float4 f = feat[featBase + (size_t)idx * C4 + j];  // cached (hot)
        m.x = fmaxf(m.x, f.x);
        m.y = fmaxf(m.y, f.y);
        m.z = fmaxf(m.z, f.z);
        m.w = fmaxf(m.w, f.w);
    }

    // Coalesced float4 store, NON-TEMPORAL (never re-read; don't evict features).
    const v4f mv = { m.x, m.y, m.z, m.w };
    __builtin_nontemporal_store(mv, (v4f*)(out + (size_t)point * C4 + j));
}

extern "C" void kernel_launch(void* const* d_in, const int* in_sizes, int n_in,
                              void* d_out, int out_size, void* d_ws, size_t ws_size,
                              hipStream_t stream) {
    const float4* feat = (const float4*)d_in[0];
    const int*    cmap = (const int*)d_in[1];
    float4*       out  = (float4*)d_out;

    const int totalThreads = B * NP * 16;         // 16 lanes per point
    const int block = 256;
    const int grid  = (totalThreads + block - 1) / block;  // 8192
    gather_max_kernel<<<grid, block, 0, stream>>>(feat, cmap, out);
}